// Round 2
// baseline (3363.290 us; speedup 1.0000x reference)
//
#include <hip/hip_runtime.h>
#include <hip/hip_bf16.h>
#include <cstdint>

// BLSTM: B=32, T=1024, D=256, U=256. Gate order i,f,c,o. fwd = cols [0,4U), bwd = cols [4U,8U).
#define B_ 32
#define T_ 1024
#define D_ 256
#define U_ 256

typedef _Float16 f16;
typedef _Float16 f16x2 __attribute__((ext_vector_type(2)));
typedef _Float16 f16x4 __attribute__((ext_vector_type(4)));
typedef _Float16 f16x8 __attribute__((ext_vector_type(8)));
typedef float f32x4 __attribute__((ext_vector_type(4)));
typedef uint32_t u32x16 __attribute__((ext_vector_type(16)));

static __device__ __forceinline__ f16x2 u2h(uint32_t u) {
    return __builtin_bit_cast(f16x2, u);
}

static __device__ __forceinline__ float hsig(float v) {
    return fminf(fmaxf(fmaf(v, 0.2f, 0.5f), 0.0f), 1.0f);
}

static __device__ __forceinline__ float tanh_f(float x) {
    float e = __expf(2.0f * x);
    return 1.0f - 2.0f / (e + 1.0f);
}

// ---- prep: convert x [B*T*D] f32 -> f16 ----
__global__ void convert_x(const float* __restrict__ x, f16* __restrict__ xh) {
    int i = blockIdx.x * blockDim.x + threadIdx.x;
    float4 v = ((const float4*)x)[i];
    f16x4 o;
    o[0] = (f16)v.x; o[1] = (f16)v.y; o[2] = (f16)v.z; o[3] = (f16)v.w;
    ((f16x4*)xh)[i] = o;
}

// ---- prep: LDS-tiled transpose [256][2048] f32 -> [2048][256] f16 ----
// grid: 32 blocks (64 output-rows each), 256 threads
__global__ __launch_bounds__(256) void transpose_to_f16(const float* __restrict__ in,
                                                        f16* __restrict__ out) {
    __shared__ float tile[256][65];  // +1 pad: conflict-free col reads
    int g0 = blockIdx.x * 64;
    int tid = threadIdx.x;
#pragma unroll 4
    for (int it = 0; it < 64; ++it) {
        int idx = it * 256 + tid;
        int k = idx >> 6;          // 0..255
        int gi = idx & 63;         // 0..63
        tile[k][gi] = in[k * 2048 + g0 + gi];
    }
    __syncthreads();
#pragma unroll 4
    for (int it = 0; it < 64; ++it) {
        int idx = it * 256 + tid;
        int gi = idx >> 8;         // 0..63
        int k = idx & 255;         // 0..255
        out[(size_t)(g0 + gi) * 256 + k] = (f16)tile[k][gi];
    }
}

// ---- phase 1: xg[t][b][g] = sum_d x[b][t][d] * kernel[d][g]  (MFMA, LDS-free) ----
__global__ __launch_bounds__(256) void gemm_xk(const f16* __restrict__ A,   // [32768][256]
                                               const f16* __restrict__ Bt,  // [2048][256]
                                               f16* __restrict__ xg) {      // [1024][32][2048]
    int nb = blockIdx.x;  // 0..15 col-block (128 cols)
    int mb = blockIdx.y;  // 0..255 row-block (128 rows)
    int tid = threadIdx.x;
    int l = tid & 63, w = tid >> 6;
    int wr = w >> 1, wc = w & 1;
    int row0 = mb * 128 + wr * 64;
    int col0 = nb * 128 + wc * 64;
    int lr = l & 15, lk = (l >> 4) * 8;

    f32x4 acc[4][4] = {};
    for (int k0 = 0; k0 < 256; k0 += 32) {
        f16x8 af[4], bf[4];
#pragma unroll
        for (int mi = 0; mi < 4; mi++)
            af[mi] = *(const f16x8*)&A[(row0 + mi * 16 + lr) * 256 + k0 + lk];
#pragma unroll
        for (int ni = 0; ni < 4; ni++)
            bf[ni] = *(const f16x8*)&Bt[(col0 + ni * 16 + lr) * 256 + k0 + lk];
#pragma unroll
        for (int mi = 0; mi < 4; mi++)
#pragma unroll
            for (int ni = 0; ni < 4; ni++)
                acc[mi][ni] = __builtin_amdgcn_mfma_f32_16x16x32_f16(af[mi], bf[ni], acc[mi][ni], 0, 0, 0);
    }
#pragma unroll
    for (int mi = 0; mi < 4; mi++) {
#pragma unroll
        for (int q = 0; q < 4; q++) {
            int row = row0 + mi * 16 + (l >> 4) * 4 + q;
            int b = row >> 10, t = row & 1023;
            long obase = (long)((t << 5) + b) * 2048;
#pragma unroll
            for (int ni = 0; ni < 4; ni++) {
                int col = col0 + ni * 16 + lr;
                xg[obase + col] = (f16)acc[mi][ni][q];
            }
        }
    }
}

// ---- phase 2: recurrence. One workgroup per (direction, batch). Weights in named SSA vectors. ----
#define FD(au, bu, acc) acc = __builtin_amdgcn_fdot2(u2h(au), u2h(bu), acc, false)

// one group: 4 h-quads (32 f16 of h) x 16 weight dwords for each of the two cols
#define GRP2(WA, WB, g)                                                                 \
    {                                                                                   \
        uint4 q0 = hq[4 * (g) + 0], q1 = hq[4 * (g) + 1];                               \
        uint4 q2 = hq[4 * (g) + 2], q3 = hq[4 * (g) + 3];                               \
        FD(q0.x, (WA)[0], acc0);  FD(q0.x, (WB)[0], acc1);                              \
        FD(q0.y, (WA)[1], acc0);  FD(q0.y, (WB)[1], acc1);                              \
        FD(q0.z, (WA)[2], acc0);  FD(q0.z, (WB)[2], acc1);                              \
        FD(q0.w, (WA)[3], acc0);  FD(q0.w, (WB)[3], acc1);                              \
        FD(q1.x, (WA)[4], acc0);  FD(q1.x, (WB)[4], acc1);                              \
        FD(q1.y, (WA)[5], acc0);  FD(q1.y, (WB)[5], acc1);                              \
        FD(q1.z, (WA)[6], acc0);  FD(q1.z, (WB)[6], acc1);                              \
        FD(q1.w, (WA)[7], acc0);  FD(q1.w, (WB)[7], acc1);                              \
        FD(q2.x, (WA)[8], acc0);  FD(q2.x, (WB)[8], acc1);                              \
        FD(q2.y, (WA)[9], acc0);  FD(q2.y, (WB)[9], acc1);                              \
        FD(q2.z, (WA)[10], acc0); FD(q2.z, (WB)[10], acc1);                             \
        FD(q2.w, (WA)[11], acc0); FD(q2.w, (WB)[11], acc1);                             \
        FD(q3.x, (WA)[12], acc0); FD(q3.x, (WB)[12], acc1);                             \
        FD(q3.y, (WA)[13], acc0); FD(q3.y, (WB)[13], acc1);                             \
        FD(q3.z, (WA)[14], acc0); FD(q3.z, (WB)[14], acc1);                             \
        FD(q3.w, (WA)[15], acc0); FD(q3.w, (WB)[15], acc1);                             \
    }

__global__ __launch_bounds__(512, 1) void blstm_rec(const f16* __restrict__ xg,      // [1024][32][2048]
                                                    const uint32_t* __restrict__ wt, // [2048][128] f16-pairs
                                                    float* __restrict__ out) {       // [32][1024][512]
    __shared__ float g_lds[1024];
    __shared__ __align__(16) f16 h_lds[256];

    int bid = blockIdx.x;
    int d = bid >> 5;   // direction
    int b = bid & 31;   // batch
    int j = threadIdx.x;  // 0..511; owns gate-cols j and j+512

    const u32x16* p0 = (const u32x16*)(wt + (size_t)((d << 10) + j) * 128);
    const u32x16* p1 = (const u32x16*)(wt + (size_t)((d << 10) + 512 + j) * 128);
    u32x16 A0 = p0[0], A1 = p0[1], A2 = p0[2], A3 = p0[3];
    u32x16 A4 = p0[4], A5 = p0[5], A6 = p0[6], A7 = p0[7];
    u32x16 B0 = p1[0], B1 = p1[1], B2 = p1[2], B3 = p1[3];
    u32x16 B4 = p1[4], B5 = p1[5], B6 = p1[6], B7 = p1[7];

    float c = 0.0f;
    if (j < 256) h_lds[j] = (f16)0.0f;
    __syncthreads();

    const f16* xbase = xg + (size_t)b * 2048 + ((size_t)d << 10);
    float a0, a1;
    {
        int t0 = d ? (T_ - 1) : 0;
        a0 = (float)xbase[(size_t)t0 * 65536 + j];
        a1 = (float)xbase[(size_t)t0 * 65536 + 512 + j];
    }

    for (int s = 0; s < T_; ++s) {
        int t = d ? (T_ - 1 - s) : s;
        // prefetch next step's xg (independent of h -> hides HBM/L2 latency under the dots)
        float na0 = 0.0f, na1 = 0.0f;
        if (s + 1 < T_) {
            int tn = d ? (T_ - 2 - s) : (s + 1);
            na0 = (float)xbase[(size_t)tn * 65536 + j];
            na1 = (float)xbase[(size_t)tn * 65536 + 512 + j];
        }

        float acc0 = a0, acc1 = a1;
        const uint4* hq = (const uint4*)h_lds;  // broadcast reads (same addr across lanes)
        GRP2(A0, B0, 0)
        GRP2(A1, B1, 1)
        GRP2(A2, B2, 2)
        GRP2(A3, B3, 3)
        GRP2(A4, B4, 4)
        GRP2(A5, B5, 5)
        GRP2(A6, B6, 6)
        GRP2(A7, B7, 7)

        g_lds[j] = acc0;
        g_lds[512 + j] = acc1;
        __syncthreads();

        if (j < 256) {
            float gi = g_lds[j];
            float gf = g_lds[256 + j];
            float gm = g_lds[512 + j];
            float go = g_lds[768 + j];
            float i_ = hsig(gi), f_ = hsig(gf), m_ = tanh_f(gm), o_ = hsig(go);
            c = f_ * c + i_ * m_;
            float h = o_ * tanh_f(c);
            out[(size_t)((b << 10) + t) * 512 + (d << 8) + j] = h;
            h_lds[j] = (f16)h;
        }
        __syncthreads();

        a0 = na0;
        a1 = na1;
    }
}

extern "C" void kernel_launch(void* const* d_in, const int* in_sizes, int n_in,
                              void* d_out, int out_size, void* d_ws, size_t ws_size,
                              hipStream_t stream) {
    const float* x = (const float*)d_in[0];       // [32][1024][256]
    const float* kern = (const float*)d_in[1];    // [256][2048]
    const float* rk = (const float*)d_in[2];      // [256][2048]
    float* out = (float*)d_out;                   // [32][1024][512]

    uint8_t* ws = (uint8_t*)d_ws;
    f16* xh = (f16*)ws;                                   // 16 MB
    f16* kh_t = (f16*)(ws + (size_t)16 * 1024 * 1024);    // 1 MB
    uint32_t* wt = (uint32_t*)(ws + (size_t)17 * 1024 * 1024);  // 1 MB
    f16* xgh = (f16*)(ws + (size_t)18 * 1024 * 1024);     // 128 MB

    convert_x<<<8192, 256, 0, stream>>>(x, xh);
    transpose_to_f16<<<32, 256, 0, stream>>>(kern, kh_t);
    transpose_to_f16<<<32, 256, 0, stream>>>(rk, (f16*)wt);
    gemm_xk<<<dim3(16, 256), 256, 0, stream>>>(xh, kh_t, xgh);
    blstm_rec<<<64, 512, 0, stream>>>(xgh, wt, out);
}

// Round 3
// 1766.891 us; speedup vs baseline: 1.9035x; 1.9035x over previous
//
#include <hip/hip_runtime.h>
#include <hip/hip_bf16.h>
#include <cstdint>

// BLSTM: B=32, T=1024, D=256, U=256. Gate order i,f,c,o. fwd = cols [0,4U), bwd = [4U,8U).
#define T_ 1024

typedef _Float16 f16;
typedef _Float16 f16x2 __attribute__((ext_vector_type(2)));
typedef _Float16 f16x4 __attribute__((ext_vector_type(4)));
typedef _Float16 f16x8 __attribute__((ext_vector_type(8)));
typedef float f32x4 __attribute__((ext_vector_type(4)));

static __device__ __forceinline__ f16x2 u2h(uint32_t u) {
    return __builtin_bit_cast(f16x2, u);
}

static __device__ __forceinline__ float hsig(float v) {
    return fminf(fmaxf(fmaf(v, 0.2f, 0.5f), 0.0f), 1.0f);
}

static __device__ __forceinline__ float tanh_f(float x) {
    float e = __expf(2.0f * x);
    return 1.0f - 2.0f / (e + 1.0f);
}

// ---- prep: convert x [B*T*D] f32 -> f16 ----
__global__ void convert_x(const float* __restrict__ x, f16* __restrict__ xh) {
    int i = blockIdx.x * blockDim.x + threadIdx.x;
    float4 v = ((const float4*)x)[i];
    f16x4 o;
    o[0] = (f16)v.x; o[1] = (f16)v.y; o[2] = (f16)v.z; o[3] = (f16)v.w;
    ((f16x4*)xh)[i] = o;
}

// ---- prep: LDS-tiled transpose [256][2048] f32 -> [2048][256] f16 ----
__global__ __launch_bounds__(256) void transpose_to_f16(const float* __restrict__ in,
                                                        f16* __restrict__ out) {
    __shared__ float tile[256][65];
    int g0 = blockIdx.x * 64;
    int tid = threadIdx.x;
#pragma unroll 4
    for (int it = 0; it < 64; ++it) {
        int idx = it * 256 + tid;
        int k = idx >> 6;
        int gi = idx & 63;
        tile[k][gi] = in[k * 2048 + g0 + gi];
    }
    __syncthreads();
#pragma unroll 4
    for (int it = 0; it < 64; ++it) {
        int idx = it * 256 + tid;
        int gi = idx >> 8;
        int k = idx & 255;
        out[(size_t)(g0 + gi) * 256 + k] = (f16)tile[k][gi];
    }
}

// ---- zero the h-exchange buffer (ws is poisoned 0xAA before every launch) ----
__global__ void zero_hx(unsigned long long* __restrict__ hx) {
    int i = blockIdx.x * blockDim.x + threadIdx.x;  // 8192 words
    hx[i] = 0ull;
}

// ---- phase 1: xg[t][b][g] = sum_d x[b][t][d] * kernel[d][g]  (MFMA, LDS-free) ----
__global__ __launch_bounds__(256) void gemm_xk(const f16* __restrict__ A,   // [32768][256]
                                               const f16* __restrict__ Bt,  // [2048][256]
                                               f16* __restrict__ xg) {      // [1024][32][2048]
    int nb = blockIdx.x;
    int mb = blockIdx.y;
    int tid = threadIdx.x;
    int l = tid & 63, w = tid >> 6;
    int wr = w >> 1, wc = w & 1;
    int row0 = mb * 128 + wr * 64;
    int col0 = nb * 128 + wc * 64;
    int lr = l & 15, lk = (l >> 4) * 8;

    f32x4 acc[4][4] = {};
    for (int k0 = 0; k0 < 256; k0 += 32) {
        f16x8 af[4], bf[4];
#pragma unroll
        for (int mi = 0; mi < 4; mi++)
            af[mi] = *(const f16x8*)&A[(row0 + mi * 16 + lr) * 256 + k0 + lk];
#pragma unroll
        for (int ni = 0; ni < 4; ni++)
            bf[ni] = *(const f16x8*)&Bt[(col0 + ni * 16 + lr) * 256 + k0 + lk];
#pragma unroll
        for (int mi = 0; mi < 4; mi++)
#pragma unroll
            for (int ni = 0; ni < 4; ni++)
                acc[mi][ni] = __builtin_amdgcn_mfma_f32_16x16x32_f16(af[mi], bf[ni], acc[mi][ni], 0, 0, 0);
    }
#pragma unroll
    for (int mi = 0; mi < 4; mi++) {
#pragma unroll
        for (int q = 0; q < 4; q++) {
            int row = row0 + mi * 16 + (l >> 4) * 4 + q;
            int b = row >> 10, t = row & 1023;
            long obase = (long)((t << 5) + b) * 2048;
#pragma unroll
            for (int ni = 0; ni < 4; ni++) {
                int col = col0 + ni * 16 + lr;
                xg[obase + col] = (f16)acc[mi][ni][q];
            }
        }
    }
}

// ---- phase 2: recurrence. 128 blocks = (direction, batch, unit-half).
// Thread j -> gate (j&3), unit (j>>2) within the half. 1 weight col per thread (128 dwords, VGPR).
// Halves exchange h via self-tagged uint64 agent atomics: tag(step+1)<<32 | 2xf16.
#define FDOT(hu, wu) acc = __builtin_amdgcn_fdot2(u2h(hu), u2h(wu), acc, false)

__global__ __launch_bounds__(512, 2) void blstm_rec2(const f16* __restrict__ xg,      // [1024][32][2048]
                                                     const uint32_t* __restrict__ wt, // [2048][128]
                                                     unsigned long long* __restrict__ hx,
                                                     float* __restrict__ out) {       // [32][1024][512]
    __shared__ __align__(16) uint32_t h32[128];  // h for all 256 units as f16-pairs

    int bb = blockIdx.x;     // 0..127
    int p = bb & 63;         // pair id; partner = bb ^ 64 (same XCD under %8 round-robin)
    int hf = bb >> 6;        // my unit-half
    int d = p >> 5, b = p & 31;
    int j = threadIdx.x;     // 0..511
    int gate = j & 3, u = j >> 2;  // unit within half

    int col = (d << 10) + (gate << 8) + (hf << 7) + u;
    const uint32_t* wp = wt + (size_t)col * 128;
    const uint32_t* wpo = wp + (hf << 6);        // own-half K rows
    const uint32_t* wpp = wp + ((1 - hf) << 6);  // partner-half K rows
    uint32_t w[128];  // [0..63] own-half rows, [64..127] partner-half rows (static indices only)
#pragma unroll
    for (int k = 0; k < 64; k++) w[k] = wpo[k];
#pragma unroll
    for (int k = 0; k < 64; k++) w[64 + k] = wpp[k];

    unsigned long long* mybuf = hx + (size_t)((p << 1) + hf) * 64;
    const unsigned long long* pbuf = hx + (size_t)((p << 1) + (1 - hf)) * 64;

    if (j < 128) h32[j] = 0u;

    float c = 0.0f;
    const f16* xgb = xg + (size_t)b * 2048 + col;
    int t0 = d ? (T_ - 1) : 0;
    float a = (float)xgb[(size_t)t0 << 11 << 5];  // t*65536
    __syncthreads();

    const uint4* hqo = ((const uint4*)h32) + (hf << 4);
    const uint4* hqp = ((const uint4*)h32) + ((1 - hf) << 4);

    for (int s = 0; s < T_; ++s) {
        int t = d ? (T_ - 1 - s) : s;
        // prefetch next step's xg (h-independent)
        float anext = 0.0f;
        if (s + 1 < T_) {
            int tn = d ? (T_ - 2 - s) : (s + 1);
            anext = (float)xgb[(size_t)tn << 16];
        }

        float acc = a;
        // phase A: dot over OWN half of h (available since end of previous step)
#pragma unroll
        for (int q = 0; q < 16; q++) {
            uint4 hv = hqo[q];
            FDOT(hv.x, w[4 * q + 0]);
            FDOT(hv.y, w[4 * q + 1]);
            FDOT(hv.z, w[4 * q + 2]);
            FDOT(hv.w, w[4 * q + 3]);
        }
        // wave 0: receive partner half h(s) (tag == s), stage into LDS
        if (s && j < 64) {
            unsigned long long v;
            do {
                v = __hip_atomic_load(&pbuf[j], __ATOMIC_RELAXED, __HIP_MEMORY_SCOPE_AGENT);
            } while ((uint32_t)(v >> 32) != (uint32_t)s);
            h32[((1 - hf) << 6) + j] = (uint32_t)v;
        }
        __syncthreads();
        // phase C: dot over PARTNER half of h
#pragma unroll
        for (int q = 0; q < 16; q++) {
            uint4 hv = hqp[q];
            FDOT(hv.x, w[64 + 4 * q + 0]);
            FDOT(hv.y, w[64 + 4 * q + 1]);
            FDOT(hv.z, w[64 + 4 * q + 2]);
            FDOT(hv.w, w[64 + 4 * q + 3]);
        }

        // in-wave gate gather: lanes j^1, j^2, j^3 hold the other 3 gates of unit u
        float g0 = acc;
        float g1 = __shfl_xor(g0, 1);
        float g2 = __shfl_xor(g0, 2);
        float g3 = __shfl_xor(g1, 2);  // from lane j^3
        // value from lane j^n has gate (gate^n); select by origin gate
        bool b0 = gate & 1, b1 = gate & 2;
        float lo = b0 ? g1 : g0, hi = b0 ? g3 : g2;
        float lo2 = b0 ? g0 : g1, hi2 = b0 ? g2 : g3;
        float gi = b1 ? hi : lo, gf = b1 ? hi2 : lo2;
        float gm = b1 ? lo : hi, go = b1 ? lo2 : hi2;

        float iv = hsig(gi), fv = hsig(gf), mv = tanh_f(gm), ov = hsig(go);
        c = fv * c + iv * mv;               // replicated consistently across the 4 gate lanes
        float h = ov * tanh_f(c);

        if (gate == 0)
            out[(size_t)((b << 10) + t) * 512 + (d << 8) + (hf << 7) + u] = h;

        // pack h pair (units u, u^1 live on lanes j, j^4), update own LDS half + publish
        uint32_t hb = (uint32_t)__builtin_bit_cast(uint16_t, (f16)h);
        uint32_t ob = __shfl_xor(hb, 4);
        if ((j & 7) == 0) {
            uint32_t word = hb | (ob << 16);
            h32[(hf << 6) + (j >> 3)] = word;
            __hip_atomic_store(&mybuf[j >> 3],
                               ((unsigned long long)(uint32_t)(s + 1) << 32) | (unsigned long long)word,
                               __ATOMIC_RELAXED, __HIP_MEMORY_SCOPE_AGENT);
        }
        a = anext;
        __syncthreads();
    }
}

extern "C" void kernel_launch(void* const* d_in, const int* in_sizes, int n_in,
                              void* d_out, int out_size, void* d_ws, size_t ws_size,
                              hipStream_t stream) {
    const float* x = (const float*)d_in[0];       // [32][1024][256]
    const float* kern = (const float*)d_in[1];    // [256][2048]
    const float* rk = (const float*)d_in[2];      // [256][2048]
    float* out = (float*)d_out;                   // [32][1024][512]

    uint8_t* ws = (uint8_t*)d_ws;
    f16* xh = (f16*)ws;                                         // 16 MB
    f16* kh_t = (f16*)(ws + (size_t)16 * 1024 * 1024);          // 1 MB
    uint32_t* wt = (uint32_t*)(ws + (size_t)17 * 1024 * 1024);  // 1 MB
    f16* xgh = (f16*)(ws + (size_t)18 * 1024 * 1024);           // 128 MB
    unsigned long long* hx = (unsigned long long*)(ws + (size_t)146 * 1024 * 1024);  // 64 KB

    convert_x<<<8192, 256, 0, stream>>>(x, xh);
    transpose_to_f16<<<32, 256, 0, stream>>>(kern, kh_t);
    transpose_to_f16<<<32, 256, 0, stream>>>(rk, (f16*)wt);
    gemm_xk<<<dim3(16, 256), 256, 0, stream>>>(xh, kh_t, xgh);
    zero_hx<<<16, 512, 0, stream>>>(hx);
    blstm_rec2<<<128, 512, 0, stream>>>(xgh, wt, hx, out);
}

// Round 5
// 1740.228 us; speedup vs baseline: 1.9327x; 1.0153x over previous
//
#include <hip/hip_runtime.h>
#include <hip/hip_bf16.h>
#include <cstdint>

// BLSTM: B=32, T=1024, D=256, U=256. Gate order i,f,c,o. fwd = cols [0,4U), bwd = [4U,8U).
#define T_ 1024

typedef _Float16 f16;
typedef _Float16 f16x2 __attribute__((ext_vector_type(2)));
typedef _Float16 f16x4 __attribute__((ext_vector_type(4)));
typedef _Float16 f16x8 __attribute__((ext_vector_type(8)));
typedef float f32x4 __attribute__((ext_vector_type(4)));
typedef uint32_t u32x16 __attribute__((ext_vector_type(16)));

static __device__ __forceinline__ f16x2 u2h(uint32_t u) {
    return __builtin_bit_cast(f16x2, u);
}

static __device__ __forceinline__ float hsig(float v) {
    return fminf(fmaxf(fmaf(v, 0.2f, 0.5f), 0.0f), 1.0f);
}

static __device__ __forceinline__ float tanh_f(float x) {
    float e = __expf(2.0f * x);
    return 1.0f - 2.0f / (e + 1.0f);
}

// ---- prep: convert x [B*T*D] f32 -> f16 ----
__global__ void convert_x(const float* __restrict__ x, f16* __restrict__ xh) {
    int i = blockIdx.x * blockDim.x + threadIdx.x;
    float4 v = ((const float4*)x)[i];
    f16x4 o;
    o[0] = (f16)v.x; o[1] = (f16)v.y; o[2] = (f16)v.z; o[3] = (f16)v.w;
    ((f16x4*)xh)[i] = o;
}

// ---- prep: LDS-tiled transpose [256][2048] f32 -> [2048][256] f16 ----
__global__ __launch_bounds__(256) void transpose_to_f16(const float* __restrict__ in,
                                                        f16* __restrict__ out) {
    __shared__ float tile[256][65];
    int g0 = blockIdx.x * 64;
    int tid = threadIdx.x;
#pragma unroll 4
    for (int it = 0; it < 64; ++it) {
        int idx = it * 256 + tid;
        int k = idx >> 6;
        int gi = idx & 63;
        tile[k][gi] = in[k * 2048 + g0 + gi];
    }
    __syncthreads();
#pragma unroll 4
    for (int it = 0; it < 64; ++it) {
        int idx = it * 256 + tid;
        int gi = idx >> 8;
        int k = idx & 255;
        out[(size_t)(g0 + gi) * 256 + k] = (f16)tile[k][gi];
    }
}

// ---- zero the h-exchange buffer (ws is poisoned 0xAA before every launch) ----
__global__ void zero_hx(unsigned long long* __restrict__ hx) {
    int i = blockIdx.x * blockDim.x + threadIdx.x;  // 16384 words (both parities)
    hx[i] = 0ull;
}

// ---- phase 1: xg[t][b][g] = sum_d x[b][t][d] * kernel[d][g]  (MFMA, LDS-free) ----
__global__ __launch_bounds__(256) void gemm_xk(const f16* __restrict__ A,   // [32768][256]
                                               const f16* __restrict__ Bt,  // [2048][256]
                                               f16* __restrict__ xg) {      // [1024][32][2048]
    int nb = blockIdx.x;
    int mb = blockIdx.y;
    int tid = threadIdx.x;
    int l = tid & 63, w = tid >> 6;
    int wr = w >> 1, wc = w & 1;
    int row0 = mb * 128 + wr * 64;
    int col0 = nb * 128 + wc * 64;
    int lr = l & 15, lk = (l >> 4) * 8;

    f32x4 acc[4][4] = {};
    for (int k0 = 0; k0 < 256; k0 += 32) {
        f16x8 af[4], bf[4];
#pragma unroll
        for (int mi = 0; mi < 4; mi++)
            af[mi] = *(const f16x8*)&A[(row0 + mi * 16 + lr) * 256 + k0 + lk];
#pragma unroll
        for (int ni = 0; ni < 4; ni++)
            bf[ni] = *(const f16x8*)&Bt[(col0 + ni * 16 + lr) * 256 + k0 + lk];
#pragma unroll
        for (int mi = 0; mi < 4; mi++)
#pragma unroll
            for (int ni = 0; ni < 4; ni++)
                acc[mi][ni] = __builtin_amdgcn_mfma_f32_16x16x32_f16(af[mi], bf[ni], acc[mi][ni], 0, 0, 0);
    }
#pragma unroll
    for (int mi = 0; mi < 4; mi++) {
#pragma unroll
        for (int q = 0; q < 4; q++) {
            int row = row0 + mi * 16 + (l >> 4) * 4 + q;
            int b = row >> 10, t = row & 1023;
            long obase = (long)((t << 5) + b) * 2048;
#pragma unroll
            for (int ni = 0; ni < 4; ni++) {
                int col = col0 + ni * 16 + lr;
                xg[obase + col] = (f16)acc[mi][ni][q];
            }
        }
    }
}

// ---- phase 2: recurrence. 256 blocks = (dir, batch, unit-quarter[64 units]).
// Thread j: gate=(j&3), khalf=(j>>2)&1, unit uu=((j>>3)&7)+8*(j>>6). 64 weight dwords/thread
// as 4 named u32x16 (64 VGPR -> no spill). Parity double-buffered tag-exact h exchange
// via uint64 agent atomics: (tag s+1)<<32 | 2xf16, buffer selected by (s+1)&1.
#define FDOT(hu, wu, acc) acc = __builtin_amdgcn_fdot2(u2h(hu), u2h(wu), acc, false)

#define DOT4(hv, W, E, acc)                \
    FDOT(hv.x, (W)[(E) + 0], acc);         \
    FDOT(hv.y, (W)[(E) + 1], acc);         \
    FDOT(hv.z, (W)[(E) + 2], acc);         \
    FDOT(hv.w, (W)[(E) + 3], acc);

__global__ __launch_bounds__(512, 2) void blstm_rec4(const f16* __restrict__ xg,      // [1024][32][2048]
                                                     const uint32_t* __restrict__ wt, // [2048][128]
                                                     unsigned long long* __restrict__ hx,
                                                     float* __restrict__ out) {       // [32][1024][512]
    __shared__ __align__(16) uint32_t h32[128];  // h(s) for all 256 units as f16 pairs

    int bb = blockIdx.x;  // 0..255; swizzle so all 4 quarters of a pair share bb%8 (same XCD)
    int qu = (bb >> 3) & 3;              // unit-quarter
    int p = ((bb & 7) << 3) + (bb >> 5); // 0..63 = d*32+b
    int d = p >> 5, b = p & 31;
    int j = threadIdx.x;      // 0..511
    int gate = j & 3;
    int kh = (j >> 2) & 1;    // K-half
    int uu = ((j >> 3) & 7) + ((j >> 6) << 3);  // 0..63 unit within quarter

    int col = (d << 10) + (gate << 8) + (qu << 6) + uu;
    const u32x16* wp = (const u32x16*)(wt + (size_t)col * 128 + (kh << 6));
    u32x16 A0 = wp[0], A1 = wp[1], A2 = wp[2], A3 = wp[3];  // 64 dwords: K-half of one col

    unsigned long long* pub0 = hx + (size_t)((p << 2) + qu) * 32;  // parity-0 buffer
    unsigned long long* pub1 = pub0 + 256 * 32;                    // parity-1 buffer

    if (j < 128) h32[j] = 0u;

    float c = 0.0f;
    const f16* xgb = xg + (size_t)b * 2048 + col;
    int t0 = d ? (T_ - 1) : 0;
    float a = (float)xgb[(size_t)t0 << 16];
    __syncthreads();

    const uint4* hq = ((const uint4*)h32) + (kh << 4);  // my K-half: 16 uint4

    for (int s = 0; s < T_; ++s) {
        int t = d ? (T_ - 1 - s) : s;
        // prefetch next step's xg (h-independent)
        float anext = 0.0f;
        if (s + 1 < T_) {
            int tn = d ? (T_ - 2 - s) : (s + 1);
            anext = (float)xgb[(size_t)tn << 16];
        }

        // receive the 3 remote quarters of h(s) (tag == s, buffer parity s&1)
        if (s && j < 96) {
            int rq = (qu + 1 + (j >> 5)) & 3;
            int w = j & 31;
            const unsigned long long* rb =
                hx + (size_t)(((s & 1) << 8) + (p << 2) + rq) * 32;
            unsigned long long v;
            do {
                v = __hip_atomic_load(&rb[w], __ATOMIC_RELAXED, __HIP_MEMORY_SCOPE_AGENT);
            } while ((uint32_t)(v >> 32) != (uint32_t)s);
            h32[(rq << 5) + w] = (uint32_t)v;
        }
        __syncthreads();

        float accA = kh ? 0.0f : a;  // xg input counted exactly once per column
        float accB = 0.0f;
        {
            uint4 h0 = hq[0], h1 = hq[1], h2 = hq[2], h3 = hq[3];
            DOT4(h0, A0, 0, accA) DOT4(h1, A0, 4, accB)
            DOT4(h2, A0, 8, accA) DOT4(h3, A0, 12, accB)
        }
        {
            uint4 h0 = hq[4], h1 = hq[5], h2 = hq[6], h3 = hq[7];
            DOT4(h0, A1, 0, accA) DOT4(h1, A1, 4, accB)
            DOT4(h2, A1, 8, accA) DOT4(h3, A1, 12, accB)
        }
        {
            uint4 h0 = hq[8], h1 = hq[9], h2 = hq[10], h3 = hq[11];
            DOT4(h0, A2, 0, accA) DOT4(h1, A2, 4, accB)
            DOT4(h2, A2, 8, accA) DOT4(h3, A2, 12, accB)
        }
        {
            uint4 h0 = hq[12], h1 = hq[13], h2 = hq[14], h3 = hq[15];
            DOT4(h0, A3, 0, accA) DOT4(h1, A3, 4, accB)
            DOT4(h2, A3, 8, accA) DOT4(h3, A3, 12, accB)
        }
        float acc = accA + accB;
        acc += __shfl_xor(acc, 4);  // combine K-halves (partner lane j^4)

        // in-wave gate gather (lanes j^1, j^2, j^3 hold the other gates of this unit)
        float g0 = acc;
        float g1 = __shfl_xor(g0, 1);
        float g2 = __shfl_xor(g0, 2);
        float g3 = __shfl_xor(g1, 2);
        bool b0 = gate & 1, b1 = gate & 2;
        float lo = b0 ? g1 : g0, hi = b0 ? g3 : g2;
        float lo2 = b0 ? g0 : g1, hi2 = b0 ? g2 : g3;
        float gi = b1 ? hi : lo, gf = b1 ? hi2 : lo2;
        float gm = b1 ? lo : hi, go = b1 ? lo2 : hi2;

        float iv = hsig(gi), fv = hsig(gf), mv = tanh_f(gm), ov = hsig(go);
        c = fv * c + iv * mv;  // replicated consistently across the 8 lanes of this unit
        float h = ov * tanh_f(c);

        if ((j & 7) == 0)  // gate==0 && kh==0
            out[(size_t)((b << 10) + t) * 512 + (d << 8) + (qu << 6) + uu] = h;

        // pack h pair (units uu, uu+1 on lanes j, j^8), publish + own LDS section
        uint32_t hb = (uint32_t)__builtin_bit_cast(uint16_t, (f16)h);
        uint32_t ob = __shfl_xor(hb, 8);
        if ((j & 15) == 0) {  // gate==0, kh==0, uu even
            uint32_t word = hb | (ob << 16);
            int kp = uu >> 1;  // 0..31
            h32[(qu << 5) + kp] = word;
            unsigned long long* pub = ((s + 1) & 1) ? pub1 : pub0;
            __hip_atomic_store(&pub[kp],
                               ((unsigned long long)(uint32_t)(s + 1) << 32) | (unsigned long long)word,
                               __ATOMIC_RELAXED, __HIP_MEMORY_SCOPE_AGENT);
        }
        a = anext;
        __syncthreads();
    }
}

extern "C" void kernel_launch(void* const* d_in, const int* in_sizes, int n_in,
                              void* d_out, int out_size, void* d_ws, size_t ws_size,
                              hipStream_t stream) {
    const float* x = (const float*)d_in[0];       // [32][1024][256]
    const float* kern = (const float*)d_in[1];    // [256][2048]
    const float* rk = (const float*)d_in[2];      // [256][2048]
    float* out = (float*)d_out;                   // [32][1024][512]

    uint8_t* ws = (uint8_t*)d_ws;
    f16* xh = (f16*)ws;                                         // 16 MB
    f16* kh_t = (f16*)(ws + (size_t)16 * 1024 * 1024);          // 1 MB
    uint32_t* wt = (uint32_t*)(ws + (size_t)17 * 1024 * 1024);  // 1 MB
    f16* xgh = (f16*)(ws + (size_t)18 * 1024 * 1024);           // 128 MB
    unsigned long long* hx = (unsigned long long*)(ws + (size_t)146 * 1024 * 1024);  // 128 KB

    convert_x<<<8192, 256, 0, stream>>>(x, xh);
    transpose_to_f16<<<32, 256, 0, stream>>>(kern, kh_t);
    transpose_to_f16<<<32, 256, 0, stream>>>(rk, (f16*)wt);
    gemm_xk<<<dim3(16, 256), 256, 0, stream>>>(xh, kh_t, xgh);
    zero_hx<<<32, 512, 0, stream>>>(hx);
    blstm_rec4<<<256, 512, 0, stream>>>(xgh, wt, hx, out);
}

// Round 6
// 1600.730 us; speedup vs baseline: 2.1011x; 1.0871x over previous
//
#include <hip/hip_runtime.h>
#include <hip/hip_bf16.h>
#include <cstdint>

// BLSTM: B=32, T=1024, D=256, U=256. Gate order i,f,c,o. fwd = cols [0,4U), bwd = [4U,8U).
#define T_ 1024

typedef _Float16 f16;
typedef _Float16 f16x2 __attribute__((ext_vector_type(2)));
typedef _Float16 f16x4 __attribute__((ext_vector_type(4)));
typedef _Float16 f16x8 __attribute__((ext_vector_type(8)));
typedef float f32x4 __attribute__((ext_vector_type(4)));
typedef uint32_t u32x16 __attribute__((ext_vector_type(16)));

static __device__ __forceinline__ f16x2 u2h(uint32_t u) {
    return __builtin_bit_cast(f16x2, u);
}

static __device__ __forceinline__ float hsig(float v) {
    return fminf(fmaxf(fmaf(v, 0.2f, 0.5f), 0.0f), 1.0f);
}

static __device__ __forceinline__ float tanh_f(float x) {
    float e = __expf(2.0f * x);
    return 1.0f - 2.0f / (e + 1.0f);
}

// ---- prep: convert x [B*T*D] f32 -> f16 ----
__global__ void convert_x(const float* __restrict__ x, f16* __restrict__ xh) {
    int i = blockIdx.x * blockDim.x + threadIdx.x;
    float4 v = ((const float4*)x)[i];
    f16x4 o;
    o[0] = (f16)v.x; o[1] = (f16)v.y; o[2] = (f16)v.z; o[3] = (f16)v.w;
    ((f16x4*)xh)[i] = o;
}

// ---- prep: LDS-tiled transpose [256][2048] f32 -> [2048][256] f16 ----
__global__ __launch_bounds__(256) void transpose_to_f16(const float* __restrict__ in,
                                                        f16* __restrict__ out) {
    __shared__ float tile[256][65];
    int g0 = blockIdx.x * 64;
    int tid = threadIdx.x;
#pragma unroll 4
    for (int it = 0; it < 64; ++it) {
        int idx = it * 256 + tid;
        int k = idx >> 6;
        int gi = idx & 63;
        tile[k][gi] = in[k * 2048 + g0 + gi];
    }
    __syncthreads();
#pragma unroll 4
    for (int it = 0; it < 64; ++it) {
        int idx = it * 256 + tid;
        int gi = idx >> 8;
        int k = idx & 255;
        out[(size_t)(g0 + gi) * 256 + k] = (f16)tile[k][gi];
    }
}

// ---- zero the h-exchange buffer (ws is poisoned 0xAA before every launch) ----
__global__ void zero_hx(unsigned long long* __restrict__ hx) {
    int i = blockIdx.x * blockDim.x + threadIdx.x;  // 16384 words (both parities)
    hx[i] = 0ull;
}

// ---- phase 1: xg[t][b][g] = sum_d x[b][t][d] * kernel[d][g]  (MFMA, LDS-free) ----
__global__ __launch_bounds__(256) void gemm_xk(const f16* __restrict__ A,   // [32768][256]
                                               const f16* __restrict__ Bt,  // [2048][256]
                                               f16* __restrict__ xg) {      // [1024][32][2048]
    int nb = blockIdx.x;
    int mb = blockIdx.y;
    int tid = threadIdx.x;
    int l = tid & 63, w = tid >> 6;
    int wr = w >> 1, wc = w & 1;
    int row0 = mb * 128 + wr * 64;
    int col0 = nb * 128 + wc * 64;
    int lr = l & 15, lk = (l >> 4) * 8;

    f32x4 acc[4][4] = {};
    for (int k0 = 0; k0 < 256; k0 += 32) {
        f16x8 af[4], bf[4];
#pragma unroll
        for (int mi = 0; mi < 4; mi++)
            af[mi] = *(const f16x8*)&A[(row0 + mi * 16 + lr) * 256 + k0 + lk];
#pragma unroll
        for (int ni = 0; ni < 4; ni++)
            bf[ni] = *(const f16x8*)&Bt[(col0 + ni * 16 + lr) * 256 + k0 + lk];
#pragma unroll
        for (int mi = 0; mi < 4; mi++)
#pragma unroll
            for (int ni = 0; ni < 4; ni++)
                acc[mi][ni] = __builtin_amdgcn_mfma_f32_16x16x32_f16(af[mi], bf[ni], acc[mi][ni], 0, 0, 0);
    }
#pragma unroll
    for (int mi = 0; mi < 4; mi++) {
#pragma unroll
        for (int q = 0; q < 4; q++) {
            int row = row0 + mi * 16 + (l >> 4) * 4 + q;
            int b = row >> 10, t = row & 1023;
            long obase = (long)((t << 5) + b) * 2048;
#pragma unroll
            for (int ni = 0; ni < 4; ni++) {
                int col = col0 + ni * 16 + lr;
                xg[obase + col] = (f16)acc[mi][ni][q];
            }
        }
    }
}

// ---- phase 2: recurrence. 256 blocks = (dir, batch, unit-quarter[64 units]).
// Thread j: gate=(j&3), khalf=(j>>2)&1, unit uu=((j>>3)&7)+8*(j>>6). 64 weight dwords/thread
// as 4 u32x16 PINNED in VGPRs via empty asm (compiler must not re-load from L2 per step).
// Parity double-buffered tag-exact h exchange via uint64 agent atomics.
// LDS h layout padded: [64 dwords half0][4 pad][64 dwords half1] so the two per-wave
// broadcast addresses (kh=0 at +0, kh=1 at +272B) hit disjoint banks.
#define FDOT(hu, wu, acc) acc = __builtin_amdgcn_fdot2(u2h(hu), u2h(wu), acc, false)

#define DOT4(hv, W, E, acc)                \
    FDOT(hv.x, (W)[(E) + 0], acc);         \
    FDOT(hv.y, (W)[(E) + 1], acc);         \
    FDOT(hv.z, (W)[(E) + 2], acc);         \
    FDOT(hv.w, (W)[(E) + 3], acc);

__global__ __launch_bounds__(512)
__attribute__((amdgpu_waves_per_eu(2, 2)))
void blstm_rec4(const f16* __restrict__ xg,      // [1024][32][2048]
                const uint32_t* __restrict__ wt, // [2048][128]
                unsigned long long* __restrict__ hx,
                float* __restrict__ out) {       // [32][1024][512]
    __shared__ __align__(16) uint32_t h32[136];  // padded: half0 @0, half1 @68

    int bb = blockIdx.x;  // 0..255; swizzle so all 4 quarters of a pair share bb%8 (same XCD)
    int qu = (bb >> 3) & 3;              // unit-quarter
    int p = ((bb & 7) << 3) + (bb >> 5); // 0..63 = d*32+b
    int d = p >> 5, b = p & 31;
    int j = threadIdx.x;      // 0..511
    int gate = j & 3;
    int kh = (j >> 2) & 1;    // K-half
    int uu = ((j >> 3) & 7) + ((j >> 6) << 3);  // 0..63 unit within quarter

    int col = (d << 10) + (gate << 8) + (qu << 6) + uu;
    const u32x16* wp = (const u32x16*)(wt + (size_t)col * 128 + (kh << 6));
    u32x16 A0 = wp[0], A1 = wp[1], A2 = wp[2], A3 = wp[3];  // 64 dwords: K-half of one col
    // pin in VGPRs: values become asm-defined -> cannot be rematerialized from memory
    asm volatile("" : "+v"(A0), "+v"(A1), "+v"(A2), "+v"(A3));

    unsigned long long* pub0 = hx + (size_t)((p << 2) + qu) * 32;  // parity-0 buffer
    unsigned long long* pub1 = pub0 + 256 * 32;                    // parity-1 buffer

    if (j < 136) h32[j] = 0u;

    float c = 0.0f;
    const f16* xgb = xg + (size_t)b * 2048 + col;
    int t0 = d ? (T_ - 1) : 0;
    float a = (float)xgb[(size_t)t0 << 16];
    __syncthreads();

    const uint4* hq = (const uint4*)(h32 + (kh ? 68 : 0));  // my K-half: 16 uint4

    for (int s = 0; s < T_; ++s) {
        int t = d ? (T_ - 1 - s) : s;
        // prefetch next step's xg (h-independent)
        float anext = 0.0f;
        if (s + 1 < T_) {
            int tn = d ? (T_ - 2 - s) : (s + 1);
            anext = (float)xgb[(size_t)tn << 16];
        }

        // receive the 3 remote quarters of h(s) (tag == s, buffer parity s&1)
        if (s && j < 96) {
            int rq = (qu + 1 + (j >> 5)) & 3;
            int w = j & 31;
            const unsigned long long* rb =
                hx + (size_t)(((s & 1) << 8) + (p << 2) + rq) * 32;
            unsigned long long v;
            do {
                v = __hip_atomic_load(&rb[w], __ATOMIC_RELAXED, __HIP_MEMORY_SCOPE_AGENT);
            } while ((uint32_t)(v >> 32) != (uint32_t)s);
            int idx = (rq << 5) + w;
            h32[idx + ((idx >> 4) & 4)] = (uint32_t)v;
        }
        __syncthreads();

        float accA = kh ? 0.0f : a;  // xg input counted exactly once per column
        float accB = 0.0f;
        {
            uint4 h0 = hq[0], h1 = hq[1], h2 = hq[2], h3 = hq[3];
            DOT4(h0, A0, 0, accA) DOT4(h1, A0, 4, accB)
            DOT4(h2, A0, 8, accA) DOT4(h3, A0, 12, accB)
        }
        {
            uint4 h0 = hq[4], h1 = hq[5], h2 = hq[6], h3 = hq[7];
            DOT4(h0, A1, 0, accA) DOT4(h1, A1, 4, accB)
            DOT4(h2, A1, 8, accA) DOT4(h3, A1, 12, accB)
        }
        {
            uint4 h0 = hq[8], h1 = hq[9], h2 = hq[10], h3 = hq[11];
            DOT4(h0, A2, 0, accA) DOT4(h1, A2, 4, accB)
            DOT4(h2, A2, 8, accA) DOT4(h3, A2, 12, accB)
        }
        {
            uint4 h0 = hq[12], h1 = hq[13], h2 = hq[14], h3 = hq[15];
            DOT4(h0, A3, 0, accA) DOT4(h1, A3, 4, accB)
            DOT4(h2, A3, 8, accA) DOT4(h3, A3, 12, accB)
        }
        float acc = accA + accB;
        acc += __shfl_xor(acc, 4);  // combine K-halves (partner lane j^4)

        // in-wave gate gather (lanes j^1, j^2, j^3 hold the other gates of this unit)
        float g0 = acc;
        float g1 = __shfl_xor(g0, 1);
        float g2 = __shfl_xor(g0, 2);
        float g3 = __shfl_xor(g1, 2);
        bool b0 = gate & 1, b1 = gate & 2;
        float lo = b0 ? g1 : g0, hi = b0 ? g3 : g2;
        float lo2 = b0 ? g0 : g1, hi2 = b0 ? g2 : g3;
        float gi = b1 ? hi : lo, gf = b1 ? hi2 : lo2;
        float gm = b1 ? lo : hi, go = b1 ? lo2 : hi2;

        float iv = hsig(gi), fv = hsig(gf), mv = tanh_f(gm), ov = hsig(go);
        c = fv * c + iv * mv;  // replicated consistently across the 8 lanes of this unit
        float h = ov * tanh_f(c);

        if ((j & 7) == 0)  // gate==0 && kh==0
            out[(size_t)((b << 10) + t) * 512 + (d << 8) + (qu << 6) + uu] = h;

        // pack h pair (units uu, uu+1 on lanes j, j^8), publish + own LDS section
        uint32_t hb = (uint32_t)__builtin_bit_cast(uint16_t, (f16)h);
        uint32_t ob = __shfl_xor(hb, 8);
        if ((j & 15) == 0) {  // gate==0, kh==0, uu even
            uint32_t word = hb | (ob << 16);
            int kp = uu >> 1;  // 0..31
            int idx = (qu << 5) + kp;
            h32[idx + ((idx >> 4) & 4)] = word;
            unsigned long long* pub = ((s + 1) & 1) ? pub1 : pub0;
            __hip_atomic_store(&pub[kp],
                               ((unsigned long long)(uint32_t)(s + 1) << 32) | (unsigned long long)word,
                               __ATOMIC_RELAXED, __HIP_MEMORY_SCOPE_AGENT);
        }
        a = anext;
        __syncthreads();
    }
}

extern "C" void kernel_launch(void* const* d_in, const int* in_sizes, int n_in,
                              void* d_out, int out_size, void* d_ws, size_t ws_size,
                              hipStream_t stream) {
    const float* x = (const float*)d_in[0];       // [32][1024][256]
    const float* kern = (const float*)d_in[1];    // [256][2048]
    const float* rk = (const float*)d_in[2];      // [256][2048]
    float* out = (float*)d_out;                   // [32][1024][512]

    uint8_t* ws = (uint8_t*)d_ws;
    f16* xh = (f16*)ws;                                         // 16 MB
    f16* kh_t = (f16*)(ws + (size_t)16 * 1024 * 1024);          // 1 MB
    uint32_t* wt = (uint32_t*)(ws + (size_t)17 * 1024 * 1024);  // 1 MB
    f16* xgh = (f16*)(ws + (size_t)18 * 1024 * 1024);           // 128 MB
    unsigned long long* hx = (unsigned long long*)(ws + (size_t)146 * 1024 * 1024);  // 128 KB

    convert_x<<<8192, 256, 0, stream>>>(x, xh);
    transpose_to_f16<<<32, 256, 0, stream>>>(kern, kh_t);
    transpose_to_f16<<<32, 256, 0, stream>>>(rk, (f16*)wt);
    gemm_xk<<<dim3(16, 256), 256, 0, stream>>>(xh, kh_t, xgh);
    zero_hx<<<32, 512, 0, stream>>>(hx);
    blstm_rec4<<<256, 512, 0, stream>>>(xgh, wt, hx, out);
}